// Round 1
// baseline (72.651 us; speedup 1.0000x reference)
//
#include <hip/hip_runtime.h>
#include <hip/hip_bf16.h>

constexpr int B = 4;
constexpr int N = 50000;
constexpr int K = 128;
constexpr int S = 256;
constexpr int NCH = (N + 255) / 256;   // 196 chunks of 256 points
constexpr float EPS = 1e-5f;

// ---------------------------------------------------------------------------
// Kernel A: one block per (b,k). Gather S=256 selected points, reduce the 16
// weighted sums (W, Σwp, Σwq, Σw p⊗q), then thread 0 runs Horn's quaternion
// method (Jacobi eigensolve of the 4x4 N matrix) -> optimal proper rotation.
// ---------------------------------------------------------------------------
__global__ __launch_bounds__(256) void procrustes_kernel(
    const float* __restrict__ src, const float* __restrict__ tgt,
    const float* __restrict__ wts, const int* __restrict__ sel,
    float* __restrict__ T)
{
  const int bk = blockIdx.x;
  const int b  = bk >> 7;        // K = 128
  const int k  = bk & (K - 1);
  const int s  = threadIdx.x;

  const int   idx = sel[k * S + s];
  const float w   = wts[b * N + idx];
  const float* ps = src + (size_t)(b * N + idx) * 3;
  const float* pt = tgt + (size_t)(b * N + idx) * 3;
  const float px = ps[0], py = ps[1], pz = ps[2];
  const float qx = pt[0], qy = pt[1], qz = pt[2];

  float acc[16];
  acc[0] = w;
  acc[1] = w * px;  acc[2] = w * py;  acc[3] = w * pz;
  acc[4] = w * qx;  acc[5] = w * qy;  acc[6] = w * qz;
  acc[7]  = w * px * qx; acc[8]  = w * px * qy; acc[9]  = w * px * qz;
  acc[10] = w * py * qx; acc[11] = w * py * qy; acc[12] = w * py * qz;
  acc[13] = w * pz * qx; acc[14] = w * pz * qy; acc[15] = w * pz * qz;

  #pragma unroll
  for (int off = 32; off > 0; off >>= 1) {
    #pragma unroll
    for (int i = 0; i < 16; ++i)
      acc[i] += __shfl_down(acc[i], off);
  }

  __shared__ float red[4][16];
  const int lane = threadIdx.x & 63, wv = threadIdx.x >> 6;
  if (lane == 0) {
    #pragma unroll
    for (int i = 0; i < 16; ++i) red[wv][i] = acc[i];
  }
  __syncthreads();

  if (threadIdx.x == 0) {
    float Sm[16];
    #pragma unroll
    for (int i = 0; i < 16; ++i)
      Sm[i] = red[0][i] + red[1][i] + red[2][i] + red[3][i];

    const float W   = Sm[0];
    const float inv = 1.f / (W + EPS);
    const float scx = Sm[1]*inv, scy = Sm[2]*inv, scz = Sm[3]*inv;
    const float tcx = Sm[4]*inv, tcy = Sm[5]*inv, tcz = Sm[6]*inv;
    // H = Σ w_n s0⊗t0 = Σ(w s⊗t)·inv − (2−σ)·sc⊗tc,  σ = W·inv
    const float f = 2.f - W * inv;
    const float Sxx = Sm[7]*inv  - f*scx*tcx;
    const float Sxy = Sm[8]*inv  - f*scx*tcy;
    const float Sxz = Sm[9]*inv  - f*scx*tcz;
    const float Syx = Sm[10]*inv - f*scy*tcx;
    const float Syy = Sm[11]*inv - f*scy*tcy;
    const float Syz = Sm[12]*inv - f*scy*tcz;
    const float Szx = Sm[13]*inv - f*scz*tcx;
    const float Szy = Sm[14]*inv - f*scz*tcy;
    const float Szz = Sm[15]*inv - f*scz*tcz;

    // Horn's 4x4 N matrix; its max-eigenvalue eigenvector is the quaternion
    // of the optimal PROPER rotation (== Kabsch with det-sign fix).
    float A[4][4], V[4][4];
    A[0][0] = Sxx + Syy + Szz;
    A[0][1] = Syz - Szy;  A[0][2] = Szx - Sxz;  A[0][3] = Sxy - Syx;
    A[1][1] = Sxx - Syy - Szz;
    A[1][2] = Sxy + Syx;  A[1][3] = Szx + Sxz;
    A[2][2] = -Sxx + Syy - Szz;
    A[2][3] = Syz + Szy;
    A[3][3] = -Sxx - Syy + Szz;
    A[1][0]=A[0][1]; A[2][0]=A[0][2]; A[3][0]=A[0][3];
    A[2][1]=A[1][2]; A[3][1]=A[1][3]; A[3][2]=A[2][3];

    #pragma unroll
    for (int i = 0; i < 4; ++i)
      #pragma unroll
      for (int j = 0; j < 4; ++j) V[i][j] = (i == j) ? 1.f : 0.f;

    for (int sweep = 0; sweep < 8; ++sweep) {
      for (int p = 0; p < 3; ++p) {
        for (int q = p + 1; q < 4; ++q) {
          const float apq = A[p][q];
          if (fabsf(apq) < 1e-18f) continue;
          const float theta = 0.5f * (A[q][q] - A[p][p]) / apq;
          const float tt = copysignf(1.f, theta) /
                           (fabsf(theta) + sqrtf(theta*theta + 1.f));
          const float c  = 1.f / sqrtf(tt*tt + 1.f);
          const float sn = tt * c;
          #pragma unroll
          for (int i = 0; i < 4; ++i) {            // A <- A J
            const float aip = A[i][p], aiq = A[i][q];
            A[i][p] = c*aip - sn*aiq;
            A[i][q] = sn*aip + c*aiq;
          }
          #pragma unroll
          for (int i = 0; i < 4; ++i) {            // A <- J^T A
            const float api = A[p][i], aqi = A[q][i];
            A[p][i] = c*api - sn*aqi;
            A[q][i] = sn*api + c*aqi;
          }
          #pragma unroll
          for (int i = 0; i < 4; ++i) {            // V <- V J
            const float vip = V[i][p], viq = V[i][q];
            V[i][p] = c*vip - sn*viq;
            V[i][q] = sn*vip + c*viq;
          }
        }
      }
    }

    int best = 0;
    #pragma unroll
    for (int i = 1; i < 4; ++i) if (A[i][i] > A[best][best]) best = i;
    float qw = V[0][best], qxv = V[1][best], qyv = V[2][best], qzv = V[3][best];
    const float qn = 1.f / sqrtf(qw*qw + qxv*qxv + qyv*qyv + qzv*qzv);
    qw *= qn; qxv *= qn; qyv *= qn; qzv *= qn;

    const float R00 = 1.f - 2.f*(qyv*qyv + qzv*qzv);
    const float R01 = 2.f*(qxv*qyv - qw*qzv);
    const float R02 = 2.f*(qxv*qzv + qw*qyv);
    const float R10 = 2.f*(qxv*qyv + qw*qzv);
    const float R11 = 1.f - 2.f*(qxv*qxv + qzv*qzv);
    const float R12 = 2.f*(qyv*qzv - qw*qxv);
    const float R20 = 2.f*(qxv*qzv - qw*qyv);
    const float R21 = 2.f*(qyv*qzv + qw*qxv);
    const float R22 = 1.f - 2.f*(qxv*qxv + qyv*qyv);

    const float tx = tcx - (R00*scx + R01*scy + R02*scz);
    const float ty = tcy - (R10*scx + R11*scy + R12*scz);
    const float tz = tcz - (R20*scx + R21*scy + R22*scz);

    float* To = T + (size_t)bk * 16;
    To[0]=R00; To[1]=R01; To[2]=R02;  To[3]=tx;
    To[4]=R10; To[5]=R11; To[6]=R12;  To[7]=ty;
    To[8]=R20; To[9]=R21; To[10]=R22; To[11]=tz;
    To[12]=0.f; To[13]=0.f; To[14]=0.f; To[15]=1.f;
  }
}

// ---------------------------------------------------------------------------
// Kernel B: one block per (b, chunk-of-256-points). Stage points in LDS;
// each thread owns one k (2 threads per k) and loops over 128 points.
// Within a wave all lanes read the SAME point -> LDS same-address broadcast.
// Per-chunk partials written without atomics -> deterministic.
// ---------------------------------------------------------------------------
__global__ __launch_bounds__(256) void error_kernel(
    const float* __restrict__ src, const float* __restrict__ tgt,
    const float* __restrict__ wts, const float* __restrict__ T,
    float* __restrict__ partial)
{
  __shared__ float4 sp[256];     // (p.xyz, w)
  __shared__ float4 sq[256];     // (q.xyz, -)
  __shared__ float  t4[K][12];   // rows 0..2 of each transform

  const int blk = blockIdx.x;
  const int b   = blk / NCH;
  const int ch  = blk - b * NCH;
  const int tid = threadIdx.x;
  const int j   = ch * 256 + tid;

  float4 P = make_float4(0.f, 0.f, 0.f, 0.f);
  float4 Q = make_float4(0.f, 0.f, 0.f, 0.f);
  if (j < N) {
    const float* ps = src + (size_t)(b*N + j) * 3;
    const float* pt = tgt + (size_t)(b*N + j) * 3;
    P.x = ps[0]; P.y = ps[1]; P.z = ps[2]; P.w = wts[b*N + j];
    Q.x = pt[0]; Q.y = pt[1]; Q.z = pt[2];
  }
  sp[tid] = P; sq[tid] = Q;

  if (tid < K) {
    const float* tp = T + (size_t)(b*K + tid) * 16;
    #pragma unroll
    for (int c = 0; c < 12; ++c) t4[tid][c] = tp[c];
  }
  __syncthreads();

  const int k    = tid & (K - 1);
  const int half = tid >> 7;
  const float R00=t4[k][0], R01=t4[k][1], R02=t4[k][2],  tx=t4[k][3];
  const float R10=t4[k][4], R11=t4[k][5], R12=t4[k][6],  ty=t4[k][7];
  const float R20=t4[k][8], R21=t4[k][9], R22=t4[k][10], tz=t4[k][11];

  float acc = 0.f;
  const int base = half * 128;
  #pragma unroll 4
  for (int i = 0; i < 128; ++i) {
    const float4 p = sp[base + i];
    const float4 q = sq[base + i];
    const float dx = fmaf(R00, p.x, fmaf(R01, p.y, fmaf(R02, p.z, tx))) - q.x;
    const float dy = fmaf(R10, p.x, fmaf(R11, p.y, fmaf(R12, p.z, ty))) - q.y;
    const float dz = fmaf(R20, p.x, fmaf(R21, p.y, fmaf(R22, p.z, tz))) - q.z;
    const float d2 = fmaf(dx, dx, fmaf(dy, dy, dz*dz));
    acc = fmaf(p.w, sqrtf(d2), acc);
  }

  __shared__ float red[256];
  red[tid] = acc;
  __syncthreads();
  if (tid < K)
    partial[((size_t)b * NCH + ch) * K + tid] = red[tid] + red[tid + 128];
}

// ---------------------------------------------------------------------------
// Kernel C: per batch, sum partials in a FIXED order (deterministic), argmin
// with first-occurrence tie-break, copy the winning 4x4 transform to out.
// ---------------------------------------------------------------------------
__global__ __launch_bounds__(128) void argmin_kernel(
    const float* __restrict__ partial, const float* __restrict__ T,
    float* __restrict__ out)
{
  const int b = blockIdx.x;
  const int k = threadIdx.x;

  float sum = 0.f;
  for (int c = 0; c < NCH; ++c)
    sum += partial[((size_t)b * NCH + c) * K + k];

  __shared__ float vals[K];
  __shared__ int   idxs[K];
  vals[k] = sum; idxs[k] = k;
  __syncthreads();

  for (int off = K / 2; off > 0; off >>= 1) {
    if (k < off) {
      const float other = vals[k + off];
      if (other < vals[k] || (other == vals[k] && idxs[k + off] < idxs[k])) {
        vals[k] = other; idxs[k] = idxs[k + off];
      }
    }
    __syncthreads();
  }

  const int best = idxs[0];
  if (k < 16) out[(size_t)b * 16 + k] = T[(size_t)(b * K + best) * 16 + k];
}

// ---------------------------------------------------------------------------
extern "C" void kernel_launch(void* const* d_in, const int* in_sizes, int n_in,
                              void* d_out, int out_size, void* d_ws, size_t ws_size,
                              hipStream_t stream) {
  const float* src = (const float*)d_in[0];
  const float* tgt = (const float*)d_in[1];
  const float* wts = (const float*)d_in[2];
  const int*   sel = (const int*)d_in[3];

  float* T       = (float*)d_ws;                                   // 512*16 floats
  float* partial = (float*)((char*)d_ws + (size_t)B*K*16*sizeof(float)); // B*NCH*K floats

  procrustes_kernel<<<B * K, 256, 0, stream>>>(src, tgt, wts, sel, T);
  error_kernel<<<B * NCH, 256, 0, stream>>>(src, tgt, wts, T, partial);
  argmin_kernel<<<B, K, 0, stream>>>(partial, T, (float*)d_out);
}

// Round 2
// 55.637 us; speedup vs baseline: 1.3058x; 1.3058x over previous
//
#include <hip/hip_runtime.h>
#include <hip/hip_bf16.h>

constexpr int B = 4;
constexpr int N = 50000;
constexpr int K = 128;
constexpr int S = 256;
constexpr int NCH = (N + 255) / 256;   // 196 chunks of 256 points
constexpr float EPS = 1e-5f;

__device__ __forceinline__ float frcp (float x) { return __builtin_amdgcn_rcpf(x); }
__device__ __forceinline__ float frsq (float x) { return __builtin_amdgcn_rsqf(x); }
__device__ __forceinline__ float fsqrt_(float x) { return __builtin_amdgcn_sqrtf(x); }

// ---------------------------------------------------------------------------
// Kernel A: one block per (b,k). Gather S=256 selected points, reduce the 16
// weighted sums, then thread 0 runs Horn's quaternion method (fast-intrinsic
// Jacobi eigensolve of the 4x4 N matrix) -> optimal proper rotation.
// ---------------------------------------------------------------------------
__global__ __launch_bounds__(256) void procrustes_kernel(
    const float* __restrict__ src, const float* __restrict__ tgt,
    const float* __restrict__ wts, const int* __restrict__ sel,
    float* __restrict__ T)
{
  const int bk = blockIdx.x;
  const int b  = bk >> 7;        // K = 128
  const int k  = bk & (K - 1);
  const int s  = threadIdx.x;

  const int   idx = sel[k * S + s];
  const float w   = wts[b * N + idx];
  const float* ps = src + (size_t)(b * N + idx) * 3;
  const float* pt = tgt + (size_t)(b * N + idx) * 3;
  const float px = ps[0], py = ps[1], pz = ps[2];
  const float qx = pt[0], qy = pt[1], qz = pt[2];

  float acc[16];
  acc[0] = w;
  acc[1] = w * px;  acc[2] = w * py;  acc[3] = w * pz;
  acc[4] = w * qx;  acc[5] = w * qy;  acc[6] = w * qz;
  acc[7]  = w * px * qx; acc[8]  = w * px * qy; acc[9]  = w * px * qz;
  acc[10] = w * py * qx; acc[11] = w * py * qy; acc[12] = w * py * qz;
  acc[13] = w * pz * qx; acc[14] = w * pz * qy; acc[15] = w * pz * qz;

  #pragma unroll
  for (int off = 32; off > 0; off >>= 1) {
    #pragma unroll
    for (int i = 0; i < 16; ++i)
      acc[i] += __shfl_down(acc[i], off);
  }

  __shared__ float red[4][16];
  const int lane = threadIdx.x & 63, wv = threadIdx.x >> 6;
  if (lane == 0) {
    #pragma unroll
    for (int i = 0; i < 16; ++i) red[wv][i] = acc[i];
  }
  __syncthreads();

  if (threadIdx.x == 0) {
    float Sm[16];
    #pragma unroll
    for (int i = 0; i < 16; ++i)
      Sm[i] = red[0][i] + red[1][i] + red[2][i] + red[3][i];

    const float W   = Sm[0];
    const float inv = frcp(W + EPS);
    const float scx = Sm[1]*inv, scy = Sm[2]*inv, scz = Sm[3]*inv;
    const float tcx = Sm[4]*inv, tcy = Sm[5]*inv, tcz = Sm[6]*inv;
    // H = Σ w_n s0⊗t0 = Σ(w s⊗t)·inv − (2−σ)·sc⊗tc,  σ = W·inv
    const float f = 2.f - W * inv;
    const float Sxx = Sm[7]*inv  - f*scx*tcx;
    const float Sxy = Sm[8]*inv  - f*scx*tcy;
    const float Sxz = Sm[9]*inv  - f*scx*tcz;
    const float Syx = Sm[10]*inv - f*scy*tcx;
    const float Syy = Sm[11]*inv - f*scy*tcy;
    const float Syz = Sm[12]*inv - f*scy*tcz;
    const float Szx = Sm[13]*inv - f*scz*tcx;
    const float Szy = Sm[14]*inv - f*scz*tcy;
    const float Szz = Sm[15]*inv - f*scz*tcz;

    // Horn's 4x4 N matrix; max-eigenvalue eigenvector = quaternion of the
    // optimal PROPER rotation (== Kabsch with det-sign fix).
    float A[4][4], V[4][4];
    A[0][0] = Sxx + Syy + Szz;
    A[0][1] = Syz - Szy;  A[0][2] = Szx - Sxz;  A[0][3] = Sxy - Syx;
    A[1][1] = Sxx - Syy - Szz;
    A[1][2] = Sxy + Syx;  A[1][3] = Szx + Sxz;
    A[2][2] = -Sxx + Syy - Szz;
    A[2][3] = Syz + Szy;
    A[3][3] = -Sxx - Syy + Szz;
    A[1][0]=A[0][1]; A[2][0]=A[0][2]; A[3][0]=A[0][3];
    A[2][1]=A[1][2]; A[3][1]=A[1][3]; A[3][2]=A[2][3];

    #pragma unroll
    for (int i = 0; i < 4; ++i)
      #pragma unroll
      for (int j = 0; j < 4; ++j) V[i][j] = (i == j) ? 1.f : 0.f;

    for (int sweep = 0; sweep < 5; ++sweep) {
      for (int p = 0; p < 3; ++p) {
        for (int q = p + 1; q < 4; ++q) {
          const float apq = A[p][q];
          if (fabsf(apq) < 1e-18f) continue;
          // fast-intrinsic rotation chain: rcp/sqrt/rsq are single v_* ops
          const float theta = 0.5f * (A[q][q] - A[p][p]) * frcp(apq);
          const float tt = copysignf(
              frcp(fabsf(theta) + fsqrt_(fmaf(theta, theta, 1.f))), theta);
          const float c  = frsq(fmaf(tt, tt, 1.f));
          const float sn = tt * c;
          #pragma unroll
          for (int i = 0; i < 4; ++i) {            // A <- A J
            const float aip = A[i][p], aiq = A[i][q];
            A[i][p] = c*aip - sn*aiq;
            A[i][q] = sn*aip + c*aiq;
          }
          #pragma unroll
          for (int i = 0; i < 4; ++i) {            // A <- J^T A
            const float api = A[p][i], aqi = A[q][i];
            A[p][i] = c*api - sn*aqi;
            A[q][i] = sn*api + c*aqi;
          }
          #pragma unroll
          for (int i = 0; i < 4; ++i) {            // V <- V J
            const float vip = V[i][p], viq = V[i][q];
            V[i][p] = c*vip - sn*viq;
            V[i][q] = sn*vip + c*viq;
          }
        }
      }
    }

    int best = 0;
    #pragma unroll
    for (int i = 1; i < 4; ++i) if (A[i][i] > A[best][best]) best = i;
    float qw = V[0][best], qxv = V[1][best], qyv = V[2][best], qzv = V[3][best];
    const float qn = frsq(qw*qw + qxv*qxv + qyv*qyv + qzv*qzv);
    qw *= qn; qxv *= qn; qyv *= qn; qzv *= qn;

    const float R00 = 1.f - 2.f*(qyv*qyv + qzv*qzv);
    const float R01 = 2.f*(qxv*qyv - qw*qzv);
    const float R02 = 2.f*(qxv*qzv + qw*qyv);
    const float R10 = 2.f*(qxv*qyv + qw*qzv);
    const float R11 = 1.f - 2.f*(qxv*qxv + qzv*qzv);
    const float R12 = 2.f*(qyv*qzv - qw*qxv);
    const float R20 = 2.f*(qxv*qzv - qw*qyv);
    const float R21 = 2.f*(qyv*qzv + qw*qxv);
    const float R22 = 1.f - 2.f*(qxv*qxv + qyv*qyv);

    const float tx = tcx - (R00*scx + R01*scy + R02*scz);
    const float ty = tcy - (R10*scx + R11*scy + R12*scz);
    const float tz = tcz - (R20*scx + R21*scy + R22*scz);

    float* To = T + (size_t)bk * 16;
    To[0]=R00; To[1]=R01; To[2]=R02;  To[3]=tx;
    To[4]=R10; To[5]=R11; To[6]=R12;  To[7]=ty;
    To[8]=R20; To[9]=R21; To[10]=R22; To[11]=tz;
    To[12]=0.f; To[13]=0.f; To[14]=0.f; To[15]=1.f;
  }
}

// ---------------------------------------------------------------------------
// Kernel B: one block per (b, chunk-of-256-points). Points staged in LDS.
// Each thread owns KPT=4 transforms (in 48 VGPRs) and one 32-point slice,
// so each LDS point broadcast is amortized over 4 k's (4x fewer ds_read_b128
// than 1-k-per-thread). Wave lanes span kg 0..31 x 2 slices -> at most 2
// distinct LDS addresses per read (2-way broadcast = free).
// ---------------------------------------------------------------------------
constexpr int KPT = 4;            // transforms per thread
constexpr int KG  = K / KPT;      // 32 k-groups
constexpr int NSL = 256 / KG;     // 8 point slices
constexpr int PPS = 256 / NSL;    // 32 points per slice

__global__ __launch_bounds__(256) void error_kernel(
    const float* __restrict__ src, const float* __restrict__ tgt,
    const float* __restrict__ wts, const float* __restrict__ T,
    float* __restrict__ partial)
{
  __shared__ float4 sp[256];          // (p.xyz, w)
  __shared__ float4 sq[256];          // (q.xyz, -)
  __shared__ float  t4[K][12];        // rows 0..2 of each transform
  __shared__ float  red[K][NSL + 1];  // stride 9: gcd(9,32)=1 -> conflict-free

  const int blk = blockIdx.x;
  const int b   = blk / NCH;
  const int ch  = blk - b * NCH;
  const int tid = threadIdx.x;
  const int j   = ch * 256 + tid;

  float4 P = make_float4(0.f, 0.f, 0.f, 0.f);
  float4 Q = make_float4(0.f, 0.f, 0.f, 0.f);
  if (j < N) {
    const float* ps = src + (size_t)(b*N + j) * 3;
    const float* pt = tgt + (size_t)(b*N + j) * 3;
    P.x = ps[0]; P.y = ps[1]; P.z = ps[2]; P.w = wts[b*N + j];
    Q.x = pt[0]; Q.y = pt[1]; Q.z = pt[2];
  }
  sp[tid] = P; sq[tid] = Q;

  if (tid < K) {
    const float* tp = T + (size_t)(b*K + tid) * 16;
    #pragma unroll
    for (int c = 0; c < 12; ++c) t4[tid][c] = tp[c];
  }
  __syncthreads();

  const int kg    = tid & (KG - 1);   // low bits -> lanes differ in kg
  const int slice = tid >> 5;         // wave spans 2 slices

  // Pull this thread's 4 transforms into registers.
  float R[KPT][12];
  #pragma unroll
  for (int m = 0; m < KPT; ++m) {
    const int k = kg + m * KG;
    #pragma unroll
    for (int c = 0; c < 12; ++c) R[m][c] = t4[k][c];
  }

  float acc[KPT] = {0.f, 0.f, 0.f, 0.f};
  const int base = slice * PPS;
  #pragma unroll 4
  for (int i = 0; i < PPS; ++i) {
    const float4 p = sp[base + i];
    const float4 q = sq[base + i];
    #pragma unroll
    for (int m = 0; m < KPT; ++m) {
      const float dx = fmaf(R[m][0], p.x, fmaf(R[m][1], p.y, fmaf(R[m][2],  p.z, R[m][3])))  - q.x;
      const float dy = fmaf(R[m][4], p.x, fmaf(R[m][5], p.y, fmaf(R[m][6],  p.z, R[m][7])))  - q.y;
      const float dz = fmaf(R[m][8], p.x, fmaf(R[m][9], p.y, fmaf(R[m][10], p.z, R[m][11]))) - q.z;
      const float d2 = fmaf(dx, dx, fmaf(dy, dy, dz*dz));
      acc[m] = fmaf(p.w, fsqrt_(d2), acc[m]);
    }
  }

  #pragma unroll
  for (int m = 0; m < KPT; ++m)
    red[kg + m * KG][slice] = acc[m];
  __syncthreads();

  if (tid < K) {
    float sum = 0.f;
    #pragma unroll
    for (int s2 = 0; s2 < NSL; ++s2) sum += red[tid][s2];
    partial[((size_t)b * NCH + ch) * K + tid] = sum;
  }
}

// ---------------------------------------------------------------------------
// Kernel C: per batch, sum partials in a FIXED order (deterministic), argmin
// with first-occurrence tie-break, copy the winning 4x4 transform to out.
// ---------------------------------------------------------------------------
__global__ __launch_bounds__(128) void argmin_kernel(
    const float* __restrict__ partial, const float* __restrict__ T,
    float* __restrict__ out)
{
  const int b = blockIdx.x;
  const int k = threadIdx.x;

  float sum = 0.f;
  for (int c = 0; c < NCH; ++c)
    sum += partial[((size_t)b * NCH + c) * K + k];

  __shared__ float vals[K];
  __shared__ int   idxs[K];
  vals[k] = sum; idxs[k] = k;
  __syncthreads();

  for (int off = K / 2; off > 0; off >>= 1) {
    if (k < off) {
      const float other = vals[k + off];
      if (other < vals[k] || (other == vals[k] && idxs[k + off] < idxs[k])) {
        vals[k] = other; idxs[k] = idxs[k + off];
      }
    }
    __syncthreads();
  }

  const int best = idxs[0];
  if (k < 16) out[(size_t)b * 16 + k] = T[(size_t)(b * K + best) * 16 + k];
}

// ---------------------------------------------------------------------------
extern "C" void kernel_launch(void* const* d_in, const int* in_sizes, int n_in,
                              void* d_out, int out_size, void* d_ws, size_t ws_size,
                              hipStream_t stream) {
  const float* src = (const float*)d_in[0];
  const float* tgt = (const float*)d_in[1];
  const float* wts = (const float*)d_in[2];
  const int*   sel = (const int*)d_in[3];

  float* T       = (float*)d_ws;                                   // 512*16 floats
  float* partial = (float*)((char*)d_ws + (size_t)B*K*16*sizeof(float)); // B*NCH*K floats

  procrustes_kernel<<<B * K, 256, 0, stream>>>(src, tgt, wts, sel, T);
  error_kernel<<<B * NCH, 256, 0, stream>>>(src, tgt, wts, T, partial);
  argmin_kernel<<<B, K, 0, stream>>>(partial, T, (float*)d_out);
}

// Round 3
// 45.222 us; speedup vs baseline: 1.6065x; 1.2303x over previous
//
#include <hip/hip_runtime.h>
#include <hip/hip_bf16.h>

constexpr int B = 4;
constexpr int N = 50000;
constexpr int K = 128;
constexpr int S = 256;
constexpr int NCH = (N + 255) / 256;   // 196 chunks of 256 points
constexpr float EPS = 1e-5f;

__device__ __forceinline__ float frcp  (float x) { return __builtin_amdgcn_rcpf(x); }
__device__ __forceinline__ float frsq  (float x) { return __builtin_amdgcn_rsqf(x); }
__device__ __forceinline__ float fsqrt_(float x) { return __builtin_amdgcn_sqrtf(x); }

// ---------------------------------------------------------------------------
// Kernel 0: pack (p.xyz, w) + (q.xyz, 0) into one 32B record per (b,n).
// Coalesced read/write; turns the scattered gather from ~3.3 cache lines per
// sample into exactly 1 (record never straddles a 64B line).
// ---------------------------------------------------------------------------
__global__ __launch_bounds__(256) void pack_kernel(
    const float* __restrict__ src, const float* __restrict__ tgt,
    const float* __restrict__ wts, float4* __restrict__ packed)
{
  const int i = blockIdx.x * 256 + threadIdx.x;
  if (i >= B * N) return;
  float4 P, Q;
  P.x = src[3*i]; P.y = src[3*i+1]; P.z = src[3*i+2]; P.w = wts[i];
  Q.x = tgt[3*i]; Q.y = tgt[3*i+1]; Q.z = tgt[3*i+2]; Q.w = 0.f;
  packed[2*i]     = P;
  packed[2*i + 1] = Q;
}

// ---------------------------------------------------------------------------
// Kernel 1: gather + reduce. One block per (b,k), XCD-pinned: bid&7 -> XCD,
// batch b = (bid&7)>>1 so each XCD's L2 only holds one batch's packed data.
// Each thread gathers one 32B record (1 line) and the block reduces the 16
// weighted sums (W, Σwp, Σwq, Σw p⊗q) to ws. NO solve here (that was the
// scratch-serialized 42µs tail in R1/R2).
// ---------------------------------------------------------------------------
template<bool PACKED>
__global__ __launch_bounds__(256) void gather_reduce_kernel(
    const float4* __restrict__ packed,
    const float* __restrict__ src, const float* __restrict__ tgt,
    const float* __restrict__ wts, const int* __restrict__ sel,
    float* __restrict__ sums)
{
  const int bid = blockIdx.x;
  const int xcd = bid & 7;
  const int b   = xcd >> 1;                       // batch pinned to XCD pair
  const int k   = ((bid >> 3) << 1) | (xcd & 1);  // bijective over [0,128)
  const int s   = threadIdx.x;

  const int idx = sel[k * S + s];

  float px, py, pz, qx, qy, qz, w;
  if (PACKED) {
    const float4 P = packed[2 * (b * N + idx)];
    const float4 Q = packed[2 * (b * N + idx) + 1];
    px = P.x; py = P.y; pz = P.z; w = P.w;
    qx = Q.x; qy = Q.y; qz = Q.z;
  } else {
    const float* ps = src + (size_t)(b * N + idx) * 3;
    const float* pt = tgt + (size_t)(b * N + idx) * 3;
    w  = wts[b * N + idx];
    px = ps[0]; py = ps[1]; pz = ps[2];
    qx = pt[0]; qy = pt[1]; qz = pt[2];
  }

  float acc[16];
  acc[0] = w;
  acc[1] = w * px;  acc[2] = w * py;  acc[3] = w * pz;
  acc[4] = w * qx;  acc[5] = w * qy;  acc[6] = w * qz;
  acc[7]  = w * px * qx; acc[8]  = w * px * qy; acc[9]  = w * px * qz;
  acc[10] = w * py * qx; acc[11] = w * py * qy; acc[12] = w * py * qz;
  acc[13] = w * pz * qx; acc[14] = w * pz * qy; acc[15] = w * pz * qz;

  #pragma unroll
  for (int off = 32; off > 0; off >>= 1) {
    #pragma unroll
    for (int i = 0; i < 16; ++i)
      acc[i] += __shfl_down(acc[i], off);
  }

  __shared__ float red[4][16];
  const int lane = threadIdx.x & 63, wv = threadIdx.x >> 6;
  if (lane == 0) {
    #pragma unroll
    for (int i = 0; i < 16; ++i) red[wv][i] = acc[i];
  }
  __syncthreads();

  if (threadIdx.x < 16) {
    const int i = threadIdx.x;
    sums[((size_t)(b * K + k)) * 16 + i] =
        red[0][i] + red[1][i] + red[2][i] + red[3][i];
  }
}

// ---------------------------------------------------------------------------
// Kernel 2: solve. One LANE per (b,k) -> 512 parallel Jacobi eigensolves.
// CRITICAL: all array indices are compile-time constants (rot<P,Q> template,
// unrolled loops, branchless selects) so A/V live in VGPRs, not scratch.
// The R1/R2 version ran this on thread 0 per block with runtime p,q indexing
// -> private arrays spilled to scratch -> ~100K-cycle serial chain = 42µs.
// ---------------------------------------------------------------------------
template<int P, int Q>
__device__ __forceinline__ void rot(float (&A)[4][4], float (&V)[4][4])
{
  const float apq = A[P][Q];
  const float theta = 0.5f * (A[Q][Q] - A[P][P]) * frcp(apq);
  const float tt = copysignf(
      frcp(fabsf(theta) + fsqrt_(fmaf(theta, theta, 1.f))), theta);
  float c  = frsq(fmaf(tt, tt, 1.f));
  float sn = tt * c;
  const bool tiny = fabsf(apq) < 1e-20f;   // branchless no-op rotation
  c  = tiny ? 1.f : c;
  sn = tiny ? 0.f : sn;
  #pragma unroll
  for (int i = 0; i < 4; ++i) {            // A <- A J
    const float aip = A[i][P], aiq = A[i][Q];
    A[i][P] = c * aip - sn * aiq;
    A[i][Q] = sn * aip + c * aiq;
  }
  #pragma unroll
  for (int i = 0; i < 4; ++i) {            // A <- J^T A
    const float api = A[P][i], aqi = A[Q][i];
    A[P][i] = c * api - sn * aqi;
    A[Q][i] = sn * api + c * aqi;
  }
  #pragma unroll
  for (int i = 0; i < 4; ++i) {            // V <- V J
    const float vip = V[i][P], viq = V[i][Q];
    V[i][P] = c * vip - sn * viq;
    V[i][Q] = sn * vip + c * viq;
  }
}

__global__ __launch_bounds__(128) void solve_kernel(
    const float* __restrict__ sums, float* __restrict__ T)
{
  const int bk = blockIdx.x * 128 + threadIdx.x;   // [0, 512)

  const float4* s4 = (const float4*)(sums + (size_t)bk * 16);
  const float4 sA = s4[0], sB = s4[1], sC = s4[2], sD = s4[3];

  const float W   = sA.x;
  const float inv = frcp(W + EPS);
  const float scx = sA.y * inv, scy = sA.z * inv, scz = sA.w * inv;
  const float tcx = sB.x * inv, tcy = sB.y * inv, tcz = sB.z * inv;
  // H = Σ(w s⊗t)·inv − (2−σ)·sc⊗tc,  σ = W·inv
  const float f = 2.f - W * inv;
  const float Sxx = sB.w * inv - f * scx * tcx;
  const float Sxy = sC.x * inv - f * scx * tcy;
  const float Sxz = sC.y * inv - f * scx * tcz;
  const float Syx = sC.z * inv - f * scy * tcx;
  const float Syy = sC.w * inv - f * scy * tcy;
  const float Syz = sD.x * inv - f * scy * tcz;
  const float Szx = sD.y * inv - f * scz * tcx;
  const float Szy = sD.z * inv - f * scz * tcy;
  const float Szz = sD.w * inv - f * scz * tcz;

  // Horn's 4x4 N matrix; max-eigenvalue eigenvector = quaternion of the
  // optimal PROPER rotation (== Kabsch with det-sign fix).
  float A[4][4], V[4][4];
  A[0][0] = Sxx + Syy + Szz;
  A[0][1] = Syz - Szy;  A[0][2] = Szx - Sxz;  A[0][3] = Sxy - Syx;
  A[1][1] = Sxx - Syy - Szz;
  A[1][2] = Sxy + Syx;  A[1][3] = Szx + Sxz;
  A[2][2] = -Sxx + Syy - Szz;
  A[2][3] = Syz + Szy;
  A[3][3] = -Sxx - Syy + Szz;
  A[1][0] = A[0][1]; A[2][0] = A[0][2]; A[3][0] = A[0][3];
  A[2][1] = A[1][2]; A[3][1] = A[1][3]; A[3][2] = A[2][3];

  #pragma unroll
  for (int i = 0; i < 4; ++i)
    #pragma unroll
    for (int j = 0; j < 4; ++j) V[i][j] = (i == j) ? 1.f : 0.f;

  #pragma unroll 1
  for (int sweep = 0; sweep < 5; ++sweep) {
    rot<0,1>(A, V); rot<0,2>(A, V); rot<0,3>(A, V);
    rot<1,2>(A, V); rot<1,3>(A, V); rot<2,3>(A, V);
  }

  // branchless argmax of diagonal + component selects (no runtime indexing)
  const float d0 = A[0][0], d1 = A[1][1], d2 = A[2][2], d3 = A[3][3];
  const bool b1 = d1 > d0;
  const bool b3 = d3 > d2;
  const float m01 = b1 ? d1 : d0;
  const float m23 = b3 ? d3 : d2;
  const bool bb = m23 > m01;
  float qw  = bb ? (b3 ? V[0][3] : V[0][2]) : (b1 ? V[0][1] : V[0][0]);
  float qxv = bb ? (b3 ? V[1][3] : V[1][2]) : (b1 ? V[1][1] : V[1][0]);
  float qyv = bb ? (b3 ? V[2][3] : V[2][2]) : (b1 ? V[2][1] : V[2][0]);
  float qzv = bb ? (b3 ? V[3][3] : V[3][2]) : (b1 ? V[3][1] : V[3][0]);

  const float qn = frsq(qw*qw + qxv*qxv + qyv*qyv + qzv*qzv);
  qw *= qn; qxv *= qn; qyv *= qn; qzv *= qn;

  const float R00 = 1.f - 2.f*(qyv*qyv + qzv*qzv);
  const float R01 = 2.f*(qxv*qyv - qw*qzv);
  const float R02 = 2.f*(qxv*qzv + qw*qyv);
  const float R10 = 2.f*(qxv*qyv + qw*qzv);
  const float R11 = 1.f - 2.f*(qxv*qxv + qzv*qzv);
  const float R12 = 2.f*(qyv*qzv - qw*qxv);
  const float R20 = 2.f*(qxv*qzv - qw*qyv);
  const float R21 = 2.f*(qyv*qzv + qw*qxv);
  const float R22 = 1.f - 2.f*(qxv*qxv + qyv*qyv);

  const float tx = tcx - (R00*scx + R01*scy + R02*scz);
  const float ty = tcy - (R10*scx + R11*scy + R12*scz);
  const float tz = tcz - (R20*scx + R21*scy + R22*scz);

  float4* To = (float4*)(T + (size_t)bk * 16);
  To[0] = make_float4(R00, R01, R02, tx);
  To[1] = make_float4(R10, R11, R12, ty);
  To[2] = make_float4(R20, R21, R22, tz);
  To[3] = make_float4(0.f, 0.f, 0.f, 1.f);
}

// ---------------------------------------------------------------------------
// Kernel 3: error evaluation. One block per (b, chunk-of-256-points); points
// staged in LDS; each thread owns KPT=4 transforms (registers, static index)
// and a 32-point slice. Per-chunk partials, fixed order, no atomics.
// ---------------------------------------------------------------------------
constexpr int KPT = 4;            // transforms per thread
constexpr int KG  = K / KPT;      // 32 k-groups
constexpr int NSL = 256 / KG;     // 8 point slices
constexpr int PPS = 256 / NSL;    // 32 points per slice

template<bool PACKED>
__global__ __launch_bounds__(256) void error_kernel(
    const float4* __restrict__ packed,
    const float* __restrict__ src, const float* __restrict__ tgt,
    const float* __restrict__ wts, const float* __restrict__ T,
    float* __restrict__ partial)
{
  __shared__ float4 sp[256];          // (p.xyz, w)
  __shared__ float4 sq[256];          // (q.xyz, -)
  __shared__ float  t4[K][12];        // rows 0..2 of each transform
  __shared__ float  red[K][NSL + 1];  // stride 9: gcd(9,32)=1 -> conflict-free

  const int blk = blockIdx.x;
  const int b   = blk / NCH;
  const int ch  = blk - b * NCH;
  const int tid = threadIdx.x;
  const int j   = ch * 256 + tid;

  float4 P = make_float4(0.f, 0.f, 0.f, 0.f);
  float4 Q = make_float4(0.f, 0.f, 0.f, 0.f);
  if (j < N) {
    if (PACKED) {
      P = packed[2 * (b * N + j)];
      Q = packed[2 * (b * N + j) + 1];
    } else {
      const float* ps = src + (size_t)(b*N + j) * 3;
      const float* pt = tgt + (size_t)(b*N + j) * 3;
      P.x = ps[0]; P.y = ps[1]; P.z = ps[2]; P.w = wts[b*N + j];
      Q.x = pt[0]; Q.y = pt[1]; Q.z = pt[2];
    }
  }
  sp[tid] = P; sq[tid] = Q;

  if (tid < K) {
    const float* tp = T + (size_t)(b*K + tid) * 16;
    #pragma unroll
    for (int c = 0; c < 12; ++c) t4[tid][c] = tp[c];
  }
  __syncthreads();

  const int kg    = tid & (KG - 1);   // low bits -> lanes differ in kg
  const int slice = tid >> 5;         // wave spans 2 slices

  float R[KPT][12];
  #pragma unroll
  for (int m = 0; m < KPT; ++m) {
    const int k = kg + m * KG;
    #pragma unroll
    for (int c = 0; c < 12; ++c) R[m][c] = t4[k][c];
  }

  float acc[KPT] = {0.f, 0.f, 0.f, 0.f};
  const int base = slice * PPS;
  #pragma unroll 4
  for (int i = 0; i < PPS; ++i) {
    const float4 p = sp[base + i];
    const float4 q = sq[base + i];
    #pragma unroll
    for (int m = 0; m < KPT; ++m) {
      const float dx = fmaf(R[m][0], p.x, fmaf(R[m][1], p.y, fmaf(R[m][2],  p.z, R[m][3])))  - q.x;
      const float dy = fmaf(R[m][4], p.x, fmaf(R[m][5], p.y, fmaf(R[m][6],  p.z, R[m][7])))  - q.y;
      const float dz = fmaf(R[m][8], p.x, fmaf(R[m][9], p.y, fmaf(R[m][10], p.z, R[m][11]))) - q.z;
      const float d2 = fmaf(dx, dx, fmaf(dy, dy, dz*dz));
      acc[m] = fmaf(p.w, fsqrt_(d2), acc[m]);
    }
  }

  #pragma unroll
  for (int m = 0; m < KPT; ++m)
    red[kg + m * KG][slice] = acc[m];
  __syncthreads();

  if (tid < K) {
    float sum = 0.f;
    #pragma unroll
    for (int s2 = 0; s2 < NSL; ++s2) sum += red[tid][s2];
    partial[((size_t)b * NCH + ch) * K + tid] = sum;
  }
}

// ---------------------------------------------------------------------------
// Kernel 4: per batch, fixed-order partial sum, first-occurrence argmin,
// copy winning transform.
// ---------------------------------------------------------------------------
__global__ __launch_bounds__(128) void argmin_kernel(
    const float* __restrict__ partial, const float* __restrict__ T,
    float* __restrict__ out)
{
  const int b = blockIdx.x;
  const int k = threadIdx.x;

  float sum = 0.f;
  for (int c = 0; c < NCH; ++c)
    sum += partial[((size_t)b * NCH + c) * K + k];

  __shared__ float vals[K];
  __shared__ int   idxs[K];
  vals[k] = sum; idxs[k] = k;
  __syncthreads();

  for (int off = K / 2; off > 0; off >>= 1) {
    if (k < off) {
      const float other = vals[k + off];
      if (other < vals[k] || (other == vals[k] && idxs[k + off] < idxs[k])) {
        vals[k] = other; idxs[k] = idxs[k + off];
      }
    }
    __syncthreads();
  }

  const int best = idxs[0];
  if (k < 16) out[(size_t)b * 16 + k] = T[(size_t)(b * K + best) * 16 + k];
}

// ---------------------------------------------------------------------------
extern "C" void kernel_launch(void* const* d_in, const int* in_sizes, int n_in,
                              void* d_out, int out_size, void* d_ws, size_t ws_size,
                              hipStream_t stream) {
  const float* src = (const float*)d_in[0];
  const float* tgt = (const float*)d_in[1];
  const float* wts = (const float*)d_in[2];
  const int*   sel = (const int*)d_in[3];

  const size_t packed_bytes = (size_t)B * N * 2 * sizeof(float4);       // 6.4 MB
  const size_t tail_floats  = 512*16 + 512*16 + (size_t)B * NCH * K;    // sums,T,partial
  const bool fast = ws_size >= packed_bytes + tail_floats * sizeof(float);

  if (fast) {
    float4* packed  = (float4*)d_ws;
    float*  sums    = (float*)((char*)d_ws + packed_bytes);
    float*  T       = sums + 512 * 16;
    float*  partial = T + 512 * 16;

    pack_kernel<<<(B * N + 255) / 256, 256, 0, stream>>>(src, tgt, wts, packed);
    gather_reduce_kernel<true><<<B * K, 256, 0, stream>>>(
        packed, src, tgt, wts, sel, sums);
    solve_kernel<<<4, 128, 0, stream>>>(sums, T);
    error_kernel<true><<<B * NCH, 256, 0, stream>>>(
        packed, src, tgt, wts, T, partial);
    argmin_kernel<<<B, K, 0, stream>>>(partial, T, (float*)d_out);
  } else {
    float* sums    = (float*)d_ws;
    float* T       = sums + 512 * 16;
    float* partial = T + 512 * 16;

    gather_reduce_kernel<false><<<B * K, 256, 0, stream>>>(
        nullptr, src, tgt, wts, sel, sums);
    solve_kernel<<<4, 128, 0, stream>>>(sums, T);
    error_kernel<false><<<B * NCH, 256, 0, stream>>>(
        nullptr, src, tgt, wts, T, partial);
    argmin_kernel<<<B, K, 0, stream>>>(partial, T, (float*)d_out);
  }
}